// Round 6
// baseline (145.559 us; speedup 1.0000x reference)
//
#include <hip/hip_runtime.h>

typedef _Float16 f16;
typedef f16   f16x8 __attribute__((ext_vector_type(8)));
typedef float f32x4 __attribute__((ext_vector_type(4)));

#define MFMA16(a, b, c) __builtin_amdgcn_mfma_f32_16x16x32_f16((a), (b), (c), 0, 0, 0)

// ---- d_ws layout (f16 units) ----
#define IMG_W1   0         // 32768: 4 quarters (kh,nh) each [64n][128k]
#define IMG_W2   32768     // 8192:  [64n][128k]
#define IMG_GW1  40960     // 2048:  [32n][64k]        (K_A block = [0,43008) contiguous)
#define IMG_E    43008     // 4 experts * 16384: per e: ew1 (2 mh * 4096) | ew2 (2 kh * 4096)
#define IMG_SW   108544    // 4096:  [64n][64k]
#define IMG_HW1  112640    // 3 * 2048: [32n][64k]     (K_C block = [108544,118784) contiguous)
#define HB_F16   118784    // 8388608 f16: hb A-frag images [tile][m][ks][lane][8]
#define MOE_F16  8507392   // 8388608 f16: moe A-frag images
#define GWT_F16  16896000  // 524288 f32: gate weights [tile][e][row32]

#define NW 12              // waves per block

__device__ __forceinline__ float silu_f(float v) {
    return v * __builtin_amdgcn_rcpf(1.0f + __expf(-v));
}

// ============ prep: fp32 src[K][N] (ld srcN) -> f16 img[n][k ^ ((n&7)<<3)] ============
__device__ void conv_blk(const float* __restrict__ src, f16* __restrict__ dst,
                         int srcN, int k0, int n0, int KB, int NB, int tid, int nth) {
    for (int i = tid; i < KB * NB; i += nth) {
        const int kk = i / NB, nn = i - kk * NB;
        dst[nn * KB + (kk ^ ((nn & 7) << 3))] = (f16)src[(long)(k0 + kk) * srcN + n0 + nn];
    }
}

__global__ void prep_weights(const float* __restrict__ w1, const float* __restrict__ w2,
                             const float* __restrict__ gw1, const float* __restrict__ ew1,
                             const float* __restrict__ ew2, const float* __restrict__ sw,
                             const float* __restrict__ hw1, f16* __restrict__ ws) {
    const int tid = blockIdx.x * 256 + threadIdx.x;
    const int nth = gridDim.x * 256;
    for (int kh = 0; kh < 2; ++kh)
        for (int nh = 0; nh < 2; ++nh)
            conv_blk(w1, ws + IMG_W1 + (kh * 2 + nh) * 8192, 128, kh * 128, nh * 64, 128, 64, tid, nth);
    conv_blk(w2,  ws + IMG_W2,  64, 0, 0, 128, 64, tid, nth);
    conv_blk(gw1, ws + IMG_GW1, 32, 0, 0,  64, 32, tid, nth);
    for (int e = 0; e < 4; ++e)
        for (int h = 0; h < 2; ++h) {
            conv_blk(ew1 + e * 8192, ws + IMG_E + e * 16384 + h * 4096,        128, 0, h * 64, 64, 64, tid, nth);
            conv_blk(ew2 + e * 8192, ws + IMG_E + e * 16384 + 8192 + h * 4096,  64, h * 64, 0, 64, 64, tid, nth);
        }
    conv_blk(sw, ws + IMG_SW, 64, 0, 0, 64, 64, tid, nth);
    for (int h = 0; h < 3; ++h)
        conv_blk(hw1 + h * 2048, ws + IMG_HW1 + h * 2048, 32, 0, 0, 64, 32, tid, nth);
}

// ============ async global->LDS staging, 1KB chunks round-robined over 12 waves ============
#define GLL16(g, l) __builtin_amdgcn_global_load_lds(                        \
    (const __attribute__((address_space(1))) void*)(g),                     \
    (__attribute__((address_space(3))) void*)(l), 16, 0, 0)

template<int BYTES>
__device__ __forceinline__ void stage12(const f16* __restrict__ g, f16* l, int wv, int lane) {
    constexpr int CALLS = BYTES / 1024;
    #pragma unroll
    for (int ch = 0; ch < CALLS; ++ch)
        if (ch % NW == wv)
            GLL16((const char*)g + ch * 1024 + lane * 16, (char*)l + ch * 1024);
}

// ============ swizzled frag access ============
// MODE 0: weight images (read-only)  key = (n&7)<<3
// MODE 2: strip [32][64] (rw)        key = (((r>>2)&3)<<1 | (r&1))<<3
__device__ __forceinline__ int swz_key(int mode, int r) {
    if (mode == 0) return (r & 7) << 3;
    return ((((r >> 2) & 3) << 1) | (r & 1)) << 3;
}

template<int MODE>
__device__ __forceinline__ f16x8 ld_frag(const f16* base, int stride, int row_base, int k0) {
    const int lane = threadIdx.x & 63;
    const int r = row_base + (lane & 15);
    const int k = k0 + ((lane >> 4) << 3);
    return *(const f16x8*)(base + r * stride + (k ^ swz_key(MODE, r)));
}

template<int MODE>
__device__ __forceinline__ void st_frag(f16* base, int stride, int row_base, int col_base, f32x4 v) {
    const int lane = threadIdx.x & 63;
    const int c = col_base + (lane & 15);
    #pragma unroll
    for (int g = 0; g < 4; ++g) {
        const int r = row_base + ((lane >> 4) << 2) + g;
        base[r * stride + (c ^ swz_key(MODE, r))] = (f16)v[g];
    }
}

// x A-frag straight from global (fp32 -> f16)
__device__ __forceinline__ f16x8 ld_x(const float* __restrict__ xrb, int ks) {
    const int lane = threadIdx.x & 63;
    const float* p = xrb + (long)(lane & 15) * 256 + ks * 32 + ((lane >> 4) << 3);
    const float4 u = *(const float4*)p;
    const float4 w = *(const float4*)(p + 4);
    f16x8 a;
    a[0] = (f16)u.x; a[1] = (f16)u.y; a[2] = (f16)u.z; a[3] = (f16)u.w;
    a[4] = (f16)w.x; a[5] = (f16)w.y; a[6] = (f16)w.z; a[7] = (f16)w.w;
    return a;
}

__device__ __forceinline__ f32x4 reduce16(f32x4 v) {
    #pragma unroll
    for (int m = 1; m <= 8; m <<= 1) {
        f32x4 o;
        #pragma unroll
        for (int i = 0; i < 4; ++i) o[i] = __shfl_xor(v[i], m, 64);
        v += o;
    }
    return v;
}

// ===================== K_A: stem1 + LN + stem2 + gate =====================
__global__ __launch_bounds__(768, 3)
void stem_kernel(const float* __restrict__ x,   const f16* __restrict__ wsp,
                 const float* __restrict__ b1,  const float* __restrict__ lng,
                 const float* __restrict__ lnb, const float* __restrict__ b2,
                 const float* __restrict__ gb1, const float* __restrict__ gw2,
                 const float* __restrict__ gb2,
                 f16* __restrict__ hb_img, float* __restrict__ gwt_img, int NT)
{
    __shared__ __align__(16) f16 lds[43008 + NW * 2048];   // 132 KB
    f16* W1  = lds;                 // 4 quarters [64n][128k]
    f16* W2  = lds + 32768;
    f16* GW1 = lds + 40960;
    const int lane = threadIdx.x & 63;
    const int wv   = threadIdx.x >> 6;
    const int c    = lane & 15;
    const int q    = lane >> 4;
    f16* STR = lds + 43008 + wv * 2048;   // per-wave [32][64] MODE2 strip

    stage12<86016>(wsp, lds, wv, lane);   // w1+w2+gw1, contiguous image block
    __syncthreads();

    const int tile = blockIdx.x * NW + wv;
    if (tile >= NT) return;

    // ---- stem1 ----
    f32x4 acc[2][8];
    #pragma unroll
    for (int n = 0; n < 8; ++n) {
        const float bv = b1[n * 16 + c];
        f32x4 t = {bv, bv, bv, bv};
        acc[0][n] = t; acc[1][n] = t;
    }
    const float* xt = x + (long)tile * 32 * 256;
    #pragma unroll
    for (int ks = 0; ks < 8; ++ks) {
        const f16x8 a0 = ld_x(xt,            ks);
        const f16x8 a1 = ld_x(xt + 16 * 256, ks);
        const int kh = ks >> 2, ksl = ks & 3;
        #pragma unroll
        for (int nf = 0; nf < 8; ++nf) {
            const f16x8 b = ld_frag<0>(W1 + (kh * 2 + (nf >> 2)) * 8192, 128, (nf & 3) * 16, ksl * 32);
            acc[0][nf] = MFMA16(a0, b, acc[0][nf]);
            acc[1][nf] = MFMA16(a1, b, acc[1][nf]);
        }
    }

    // ---- LN stats ----
    f32x4 mu[2], rs[2];
    #pragma unroll
    for (int m = 0; m < 2; ++m) {
        f32x4 s = {0,0,0,0}, qq = {0,0,0,0};
        #pragma unroll
        for (int n = 0; n < 8; ++n) { s += acc[m][n]; qq += acc[m][n] * acc[m][n]; }
        s = reduce16(s); qq = reduce16(qq);
        mu[m] = s * 0.0078125f;
        #pragma unroll
        for (int g = 0; g < 4; ++g)
            rs[m][g] = rsqrtf(qq[g] * 0.0078125f - mu[m][g] * mu[m][g] + 1e-5f);
    }

    // ---- stem2 in two K-halves through the strip ----
    f32x4 a2[2][4];
    #pragma unroll
    for (int n = 0; n < 4; ++n) {
        const float bv = b2[n * 16 + c];
        f32x4 t = {bv, bv, bv, bv};
        a2[0][n] = t; a2[1][n] = t;
    }
    #pragma unroll
    for (int half = 0; half < 2; ++half) {
        #pragma unroll
        for (int m = 0; m < 2; ++m)
            #pragma unroll
            for (int n = 0; n < 4; ++n) {
                const int j = half * 64 + n * 16 + c;
                const float gg = lng[j], bb = lnb[j];
                f32x4 v;
                #pragma unroll
                for (int g = 0; g < 4; ++g)
                    v[g] = silu_f((acc[m][half * 4 + n][g] - mu[m][g]) * rs[m][g] * gg + bb);
                st_frag<2>(STR, 64, m * 16, n * 16, v);
            }
        #pragma unroll
        for (int ks = 0; ks < 2; ++ks) {
            const f16x8 a0 = ld_frag<2>(STR, 64, 0,  ks * 32);
            const f16x8 a1 = ld_frag<2>(STR, 64, 16, ks * 32);
            #pragma unroll
            for (int n = 0; n < 4; ++n) {
                const f16x8 b = ld_frag<0>(W2, 128, n * 16, half * 64 + ks * 32);
                a2[0][n] = MFMA16(a0, b, a2[0][n]);
                a2[1][n] = MFMA16(a1, b, a2[1][n]);
            }
        }
    }
    // hb = silu(a2) -> strip -> A-frags (regs) -> global image
    #pragma unroll
    for (int m = 0; m < 2; ++m)
        #pragma unroll
        for (int n = 0; n < 4; ++n) {
            f32x4 v;
            #pragma unroll
            for (int g = 0; g < 4; ++g) v[g] = silu_f(a2[m][n][g]);
            st_frag<2>(STR, 64, m * 16, n * 16, v);
        }
    f16x8 hbA[2][2];
    #pragma unroll
    for (int m = 0; m < 2; ++m)
        #pragma unroll
        for (int ks = 0; ks < 2; ++ks) {
            hbA[m][ks] = ld_frag<2>(STR, 64, m * 16, ks * 32);
            *(f16x8*)(hb_img + (((long)tile * 2 + m) * 2 + ks) * 512 + lane * 8) = hbA[m][ks];
        }

    // ---- gate ----
    f32x4 ag[2][2];
    #pragma unroll
    for (int n = 0; n < 2; ++n) {
        const float bv = gb1[n * 16 + c];
        f32x4 t = {bv, bv, bv, bv};
        ag[0][n] = t; ag[1][n] = t;
    }
    #pragma unroll
    for (int ks = 0; ks < 2; ++ks)
        #pragma unroll
        for (int n = 0; n < 2; ++n) {
            const f16x8 b = ld_frag<0>(GW1, 64, n * 16, ks * 32);
            ag[0][n] = MFMA16(hbA[0][ks], b, ag[0][n]);
            ag[1][n] = MFMA16(hbA[1][ks], b, ag[1][n]);
        }
    const f32x4 gb2v = *(const f32x4*)gb2;
    #pragma unroll
    for (int m = 0; m < 2; ++m) {
        f32x4 pg[4] = {{0,0,0,0},{0,0,0,0},{0,0,0,0},{0,0,0,0}};
        #pragma unroll
        for (int n = 0; n < 2; ++n) {
            const f32x4 w4 = *(const f32x4*)(gw2 + (n * 16 + c) * 4);
            #pragma unroll
            for (int g = 0; g < 4; ++g)
                pg[g] += silu_f(ag[m][n][g]) * w4;
        }
        f32x4 gwt[4];
        #pragma unroll
        for (int g = 0; g < 4; ++g) {
            f32x4 l = reduce16(pg[g]) + gb2v;
            const float mx = fmaxf(fmaxf(l[0], l[1]), fmaxf(l[2], l[3]));
            f32x4 ee;
            #pragma unroll
            for (int o = 0; o < 4; ++o) ee[o] = __expf(l[o] - mx);
            gwt[g] = ee * __builtin_amdgcn_rcpf(ee[0] + ee[1] + ee[2] + ee[3]);
        }
        if (c < 4) {   // lane writes component e = c for its rows
            float4 o;
            o.x = (c == 0) ? gwt[0][0] : (c == 1) ? gwt[0][1] : (c == 2) ? gwt[0][2] : gwt[0][3];
            o.y = (c == 0) ? gwt[1][0] : (c == 1) ? gwt[1][1] : (c == 2) ? gwt[1][2] : gwt[1][3];
            o.z = (c == 0) ? gwt[2][0] : (c == 1) ? gwt[2][1] : (c == 2) ? gwt[2][2] : gwt[2][3];
            o.w = (c == 0) ? gwt[3][0] : (c == 1) ? gwt[3][1] : (c == 2) ? gwt[3][2] : gwt[3][3];
            *(float4*)(gwt_img + ((long)tile * 4 + c) * 32 + m * 16 + q * 4) = o;
        }
    }
}

// ===================== K_B: 4 experts =====================
__global__ __launch_bounds__(768, 3)
void expert_kernel(const f16* __restrict__ wsp, const float* __restrict__ eb1,
                   const float* __restrict__ eb2,
                   const f16* __restrict__ hb_img, const float* __restrict__ gwt_img,
                   f16* __restrict__ moe_img, int NT)
{
    __shared__ __align__(16) f16 lds[32768 + NW * 2048];   // 112 KB
    f16* EW = lds;                        // 2 experts: per e_loc: ew1(8192) | ew2(8192)
    const int lane = threadIdx.x & 63;
    const int wv   = threadIdx.x >> 6;
    const int c    = lane & 15;
    const int q    = lane >> 4;
    f16* STR = lds + 32768 + wv * 2048;

    const int tile = blockIdx.x * NW + wv;
    const bool act = tile < NT;

    f16x8 hbA[2][2];
    if (act)
        #pragma unroll
        for (int m = 0; m < 2; ++m)
            #pragma unroll
            for (int ks = 0; ks < 2; ++ks)
                hbA[m][ks] = *(const f16x8*)(hb_img + (((long)tile * 2 + m) * 2 + ks) * 512 + lane * 8);

    f32x4 moe[2][4] = {{{0,0,0,0},{0,0,0,0},{0,0,0,0},{0,0,0,0}},
                       {{0,0,0,0},{0,0,0,0},{0,0,0,0},{0,0,0,0}}};

    #pragma unroll
    for (int p = 0; p < 2; ++p) {                       // expert pairs {0,1}, {2,3}
        if (p) __syncthreads();                         // prior pair's EW reads done
        stage12<65536>(wsp + IMG_E + p * 32768, EW, wv, lane);
        __syncthreads();
        if (act) {
            #pragma unroll
            for (int el = 0; el < 2; ++el) {
                const int ee = p * 2 + el;
                const f16* ebase = EW + el * 16384;
                f32x4 a2acc[2][4];
                #pragma unroll
                for (int n = 0; n < 4; ++n) {
                    const float bv = eb2[ee * 64 + n * 16 + c];
                    f32x4 t = {bv, bv, bv, bv};
                    a2acc[0][n] = t; a2acc[1][n] = t;
                }
                #pragma unroll
                for (int mh = 0; mh < 2; ++mh) {
                    f32x4 a1acc[2][4];
                    #pragma unroll
                    for (int n = 0; n < 4; ++n) {
                        const float bv = eb1[ee * 128 + mh * 64 + n * 16 + c];
                        f32x4 t = {bv, bv, bv, bv};
                        a1acc[0][n] = t; a1acc[1][n] = t;
                    }
                    #pragma unroll
                    for (int ks = 0; ks < 2; ++ks)
                        #pragma unroll
                        for (int n = 0; n < 4; ++n) {
                            const f16x8 b = ld_frag<0>(ebase + mh * 4096, 64, n * 16, ks * 32);
                            a1acc[0][n] = MFMA16(hbA[0][ks], b, a1acc[0][n]);
                            a1acc[1][n] = MFMA16(hbA[1][ks], b, a1acc[1][n]);
                        }
                    #pragma unroll
                    for (int m = 0; m < 2; ++m)
                        #pragma unroll
                        for (int n = 0; n < 4; ++n) {
                            f32x4 v;
                            #pragma unroll
                            for (int g = 0; g < 4; ++g) v[g] = silu_f(a1acc[m][n][g]);
                            st_frag<2>(STR, 64, m * 16, n * 16, v);
                        }
                    #pragma unroll
                    for (int ks = 0; ks < 2; ++ks) {
                        const f16x8 a0 = ld_frag<2>(STR, 64, 0,  ks * 32);
                        const f16x8 a1 = ld_frag<2>(STR, 64, 16, ks * 32);
                        #pragma unroll
                        for (int n = 0; n < 4; ++n) {
                            const f16x8 b = ld_frag<0>(ebase + 8192 + mh * 4096, 64, n * 16, ks * 32);
                            a2acc[0][n] = MFMA16(a0, b, a2acc[0][n]);
                            a2acc[1][n] = MFMA16(a1, b, a2acc[1][n]);
                        }
                    }
                }
                const float* gb = gwt_img + ((long)tile * 4 + ee) * 32 + q * 4;
                #pragma unroll
                for (int m = 0; m < 2; ++m) {
                    const float4 g4 = *(const float4*)(gb + m * 16);
                    #pragma unroll
                    for (int n = 0; n < 4; ++n) {
                        moe[m][n][0] += silu_f(a2acc[m][n][0]) * g4.x;
                        moe[m][n][1] += silu_f(a2acc[m][n][1]) * g4.y;
                        moe[m][n][2] += silu_f(a2acc[m][n][2]) * g4.z;
                        moe[m][n][3] += silu_f(a2acc[m][n][3]) * g4.w;
                    }
                }
            }
        }
    }
    if (!act) return;
    // moe -> strip -> A-frag image
    #pragma unroll
    for (int m = 0; m < 2; ++m)
        #pragma unroll
        for (int n = 0; n < 4; ++n)
            st_frag<2>(STR, 64, m * 16, n * 16, moe[m][n]);
    #pragma unroll
    for (int m = 0; m < 2; ++m)
        #pragma unroll
        for (int ks = 0; ks < 2; ++ks)
            *(f16x8*)(moe_img + (((long)tile * 2 + m) * 2 + ks) * 512 + lane * 8) =
                ld_frag<2>(STR, 64, m * 16, ks * 32);
}

// ===================== K_C: shared trunk + heads =====================
__global__ __launch_bounds__(768, 3)
void head_kernel(const f16* __restrict__ wsp, const float* __restrict__ sb,
                 const float* __restrict__ hb1, const float* __restrict__ hw2,
                 const float* __restrict__ hb2, const f16* __restrict__ moe_img,
                 float* __restrict__ out, int NT)
{
    __shared__ __align__(16) f16 lds[10240 + NW * 2048];   // 68 KB
    f16* SW  = lds;
    f16* HW1 = lds + 4096;
    const int lane = threadIdx.x & 63;
    const int wv   = threadIdx.x >> 6;
    const int c    = lane & 15;
    f16* STR = lds + 10240 + wv * 2048;

    stage12<20480>(wsp + IMG_SW, lds, wv, lane);
    __syncthreads();

    const int tile = blockIdx.x * NW + wv;
    if (tile >= NT) return;

    f16x8 moeA[2][2];
    #pragma unroll
    for (int m = 0; m < 2; ++m)
        #pragma unroll
        for (int ks = 0; ks < 2; ++ks)
            moeA[m][ks] = *(const f16x8*)(moe_img + (((long)tile * 2 + m) * 2 + ks) * 512 + lane * 8);

    // shared: feat = silu(moe @ sw + sb)
    f32x4 as[2][4];
    #pragma unroll
    for (int n = 0; n < 4; ++n) {
        const float bv = sb[n * 16 + c];
        f32x4 t = {bv, bv, bv, bv};
        as[0][n] = t; as[1][n] = t;
    }
    #pragma unroll
    for (int ks = 0; ks < 2; ++ks)
        #pragma unroll
        for (int n = 0; n < 4; ++n) {
            const f16x8 b = ld_frag<0>(SW, 64, n * 16, ks * 32);
            as[0][n] = MFMA16(moeA[0][ks], b, as[0][n]);
            as[1][n] = MFMA16(moeA[1][ks], b, as[1][n]);
        }
    #pragma unroll
    for (int m = 0; m < 2; ++m)
        #pragma unroll
        for (int n = 0; n < 4; ++n) {
            f32x4 v;
            #pragma unroll
            for (int g = 0; g < 4; ++g) v[g] = silu_f(as[m][n][g]);
            st_frag<2>(STR, 64, m * 16, n * 16, v);
        }
    f16x8 featA[2][2];
    #pragma unroll
    for (int m = 0; m < 2; ++m)
        #pragma unroll
        for (int ks = 0; ks < 2; ++ks)
            featA[m][ks] = ld_frag<2>(STR, 64, m * 16, ks * 32);

    // heads
    f32x4 ah[2][6];
    #pragma unroll
    for (int n = 0; n < 6; ++n) {
        const float bv = hb1[(n >> 1) * 32 + (n & 1) * 16 + c];
        f32x4 t = {bv, bv, bv, bv};
        ah[0][n] = t; ah[1][n] = t;
    }
    #pragma unroll
    for (int ks = 0; ks < 2; ++ks)
        #pragma unroll
        for (int n = 0; n < 6; ++n) {
            const f16x8 b = ld_frag<0>(HW1 + (n >> 1) * 2048, 64, (n & 1) * 16, ks * 32);
            ah[0][n] = MFMA16(featA[0][ks], b, ah[0][n]);
            ah[1][n] = MFMA16(featA[1][ks], b, ah[1][n]);
        }
    const float hb2_0 = hb2[0], hb2_1 = hb2[1], hb2_2 = hb2[2];
    #pragma unroll
    for (int m = 0; m < 2; ++m) {
        f32x4 ph[3] = {{0,0,0,0},{0,0,0,0},{0,0,0,0}};
        #pragma unroll
        for (int n = 0; n < 6; ++n) {
            const int head = n >> 1;
            const float w2v = hw2[head * 32 + (n & 1) * 16 + c];
            #pragma unroll
            for (int g = 0; g < 4; ++g)
                ph[head][g] += silu_f(ah[m][n][g]) * w2v;
        }
        #pragma unroll
        for (int h = 0; h < 3; ++h) ph[h] = reduce16(ph[h]);
        #pragma unroll
        for (int g = 0; g < 4; ++g) {
            const long row = (long)tile * 32 + m * 16 + ((lane >> 4) << 2) + g;
            if (c < 3) {
                const float r0 = ph[0][g] + hb2_0;
                const float r1 = ph[1][g] + hb2_1;
                const float r2 = ph[2][g] + hb2_2;
                out[row * 3 + c] = (c == 0) ? r0 : ((c == 1) ? r1 : r2);
            }
        }
    }
}

extern "C" void kernel_launch(void* const* d_in, const int* in_sizes, int n_in,
                              void* d_out, int out_size, void* d_ws, size_t ws_size,
                              hipStream_t stream) {
    const float* x    = (const float*)d_in[0];
    const float* w1   = (const float*)d_in[1];
    const float* b1   = (const float*)d_in[2];
    const float* lng  = (const float*)d_in[3];
    const float* lnb  = (const float*)d_in[4];
    const float* w2   = (const float*)d_in[5];
    const float* b2   = (const float*)d_in[6];
    const float* ew1  = (const float*)d_in[7];
    const float* eb1  = (const float*)d_in[8];
    const float* ew2  = (const float*)d_in[9];
    const float* eb2  = (const float*)d_in[10];
    const float* gw1  = (const float*)d_in[11];
    const float* gb1  = (const float*)d_in[12];
    const float* gw2  = (const float*)d_in[13];
    const float* gb2  = (const float*)d_in[14];
    const float* sw   = (const float*)d_in[15];
    const float* sb   = (const float*)d_in[16];
    const float* hw1  = (const float*)d_in[17];
    const float* hb1  = (const float*)d_in[18];
    const float* hw2  = (const float*)d_in[19];
    const float* hb2  = (const float*)d_in[20];
    float* out = (float*)d_out;

    f16*   ws      = (f16*)d_ws;
    f16*   hb_img  = ws + HB_F16;
    f16*   moe_img = ws + MOE_F16;
    float* gwt_img = (float*)(ws + GWT_F16);

    const int B  = in_sizes[0] / 256;
    const int NT = B / 32;
    const int grid = (NT + NW - 1) / NW;

    hipLaunchKernelGGL(prep_weights, dim3(64), dim3(256), 0, stream,
                       w1, w2, gw1, ew1, ew2, sw, hw1, ws);
    hipLaunchKernelGGL(stem_kernel, dim3(grid), dim3(NW * 64), 0, stream,
                       x, ws, b1, lng, lnb, b2, gb1, gw2, gb2, hb_img, gwt_img, NT);
    hipLaunchKernelGGL(expert_kernel, dim3(grid), dim3(NW * 64), 0, stream,
                       ws, eb1, eb2, hb_img, gwt_img, moe_img, NT);
    hipLaunchKernelGGL(head_kernel, dim3(grid), dim3(NW * 64), 0, stream,
                       ws, sb, hb1, hw2, hb2, moe_img, out, NT);
}